// Round 7
// baseline (48.105 us; speedup 1.0000x reference)
//
#include <hip/hip_runtime.h>
#include <hip/hip_cooperative_groups.h>

namespace cg = cooperative_groups;

// Masked LSTM encoder — single cooperative kernel (R6's two proven kernels
// fused across a grid.sync()).
//  - h0 = c0 = 0 -> step 0 is gates = x0 @ Wx + b; f-gate dead (sig(f)*c0 = 0).
//  - is_eos[b] |= (embedding[token][EOS_ID=1] != 0): N(0,0.02) float -> true
//    after step 0 -> state frozen at step-0 values for every batch.
//  - Phase 1 (== R6 K1): split-K GEMM partials; 64-col tiles keep every 64B Wx
//    line exclusive to one block (R5: narrow tiles -> 8x fetch amplification);
//    lane=batch -> wave-uniform scalar Wx loads; LDS transpose -> coalesced
//    [ec][b][col] stores.
//  - grid.sync() replaces the second launch (~2 us of the 13.2 us total).
//  - Phase 2 (== R6 K2): block bi < 64 owns batch bi: reduce 8 partials + bias,
//    pointwise (c0=0 -> f dead), store c,h; faithful tail in the never-taken
//    non-frozen branch stays block-local. Blocks 64..191 exit after the sync.

#define SEQ      512
#define EDIM     512
#define HDIM     512
#define BATCH    64
#define NCOMPACT 1536          // compact cols: i(0..511), g(512..1023), o(1024..1535)
#define ECHUNKS  8             // split-K factor
#define ELEN     (EDIM / ECHUNKS)   // 64
#define CTILES   (NCOMPACT / 64)    // 24

__device__ __forceinline__ float sigf(float x) { return 1.0f / (1.0f + __expf(-x)); }

__global__ __launch_bounds__(512) void fused_coop_kernel(
    const int* __restrict__ inputs, const float* __restrict__ emb,
    const float* __restrict__ Wx, const float* __restrict__ Wh,
    const float* __restrict__ bias, float* __restrict__ partials,
    float* __restrict__ out)
{
    __shared__ float x_s[ELEN][BATCH + 1];  // phase 1: [e][b]
    __shared__ float g_s[64][BATCH + 1];    // phase 1: transpose buffer
    __shared__ float c_sh[HDIM];            // phase 2 tail
    __shared__ float h_sh[HDIM];
    __shared__ float xe_s[EDIM];

    const int t    = threadIdx.x;
    const int lane = t & 63;
    const int w    = __builtin_amdgcn_readfirstlane(t >> 6);  // wave 0..7

    // ================= Phase 1: partial GEMM (R6 K1, unchanged) =================
    {
        const int ct   = blockIdx.x >> 3;      // 0..23  compact col tile
        const int ec   = blockIdx.x & 7;       // 0..7   e-chunk
        const int e0   = ec * ELEN;
        const int gate = ct >> 3;              // 0:i 1:g 2:o
        const int gofs = (gate == 0) ? 0 : (gate == 1 ? 1024 : 1536);
        const int wcol = gofs + (ct & 7) * 64 + w * 8;  // wave-uniform Wx col

        #pragma unroll
        for (int k = 0; k < 8; ++k) {
            const int b   = w * 8 + k;
            const int tok = inputs[b * SEQ];
            x_s[lane][b] = emb[(size_t)tok * EDIM + e0 + lane];
        }
        __syncthreads();

        float acc[8] = {};
        #pragma unroll 8
        for (int e = 0; e < ELEN; ++e) {
            const float xv = x_s[e][lane];                        // conflict-free
            const float* row = Wx + (size_t)(e0 + e) * 2048 + wcol;  // s_load
            #pragma unroll
            for (int wc = 0; wc < 8; ++wc)
                acc[wc] += xv * row[wc];
        }

        #pragma unroll
        for (int wc = 0; wc < 8; ++wc)
            g_s[w * 8 + wc][lane] = acc[wc];
        __syncthreads();

        #pragma unroll
        for (int k = 0; k < 8; ++k) {
            const int b = w * 8 + k;
            partials[((size_t)ec * BATCH + b) * NCOMPACT + ct * 64 + lane] = g_s[lane][b];
        }
    }

    // ================= grid-wide barrier (replaces 2nd launch) =================
    cg::this_grid().sync();

    // ================= Phase 2: pointwise + (dead) tail, block = batch ==========
    const int b = blockIdx.x;
    if (b >= BATCH) return;
    const int j = t;                          // 0..511

    float gi = bias[j];
    float gg = bias[1024 + j];
    float go = bias[1536 + j];
    #pragma unroll
    for (int ec = 0; ec < ECHUNKS; ++ec) {
        const float* p = partials + ((size_t)ec * BATCH + b) * NCOMPACT;
        gi += p[j];                           // lanes = j consecutive -> coalesced
        gg += p[512 + j];
        go += p[1024 + j];
    }
    const float c = sigf(gi) * tanhf(gg);     // c0 = 0 -> f-gate dead
    const float h = sigf(go) * tanhf(c);

    // EOS after step 0 (block-uniform broadcast loads).
    const int tok0 = inputs[b * SEQ];
    const bool frozen = (emb[(size_t)tok0 * EDIM + 1] != 0.0f);

    if (frozen) {                             // block-uniform branch
        out[b * HDIM + j]                = c;
        out[BATCH * HDIM + b * HDIM + j] = h;
        return;
    }

    // ---- Faithful sequential tail, steps 1..511 (never taken on this input).
    c_sh[j] = c;
    h_sh[j] = h;
    bool eos = false;
    __syncthreads();

    const float b0 = bias[j];
    const float b1 = bias[512 + j];
    const float b2 = bias[1024 + j];
    const float b3 = bias[1536 + j];

    for (int s = 1; s < SEQ; ++s) {
        const int tok = inputs[b * SEQ + s];
        xe_s[j] = emb[(size_t)tok * EDIM + j];
        __syncthreads();

        float g0 = b0, g1 = b1, g2 = b2, g3 = b3;
        for (int e = 0; e < EDIM; ++e) {
            const float xv = xe_s[e];
            const float hv = h_sh[e];
            const float* wxr = Wx + (size_t)e * 2048;
            const float* whr = Wh + (size_t)e * 2048;
            g0 += xv * wxr[j]        + hv * whr[j];
            g1 += xv * wxr[512 + j]  + hv * whr[512 + j];
            g2 += xv * wxr[1024 + j] + hv * whr[1024 + j];
            g3 += xv * wxr[1536 + j] + hv * whr[1536 + j];
        }
        const float nc = sigf(g1) * c_sh[j] + sigf(g0) * tanhf(g2);
        const float nh = sigf(g3) * tanhf(nc);
        eos = eos || (xe_s[1] != 0.0f);       // token s raises flag AFTER update
        __syncthreads();
        c_sh[j] = nc;
        h_sh[j] = nh;
        __syncthreads();
        if (eos) break;                       // block-uniform
    }

    out[b * HDIM + j]                = c_sh[j];
    out[BATCH * HDIM + b * HDIM + j] = h_sh[j];
}

extern "C" void kernel_launch(void* const* d_in, const int* in_sizes, int n_in,
                              void* d_out, int out_size, void* d_ws, size_t ws_size,
                              hipStream_t stream) {
    const int*   inputs = (const int*)  d_in[0];
    const float* emb    = (const float*)d_in[1];
    const float* Wx     = (const float*)d_in[2];
    const float* Wh     = (const float*)d_in[3];
    const float* bias   = (const float*)d_in[4];
    float* out      = (float*)d_out;
    float* partials = (float*)d_ws;   // ECHUNKS*BATCH*NCOMPACT floats = 3 MB

    void* args[] = {(void*)&inputs, (void*)&emb, (void*)&Wx, (void*)&Wh,
                    (void*)&bias, (void*)&partials, (void*)&out};
    hipLaunchCooperativeKernel((const void*)fused_coop_kernel,
                               dim3(CTILES * ECHUNKS), dim3(512),
                               args, 0, stream);
}

// Round 8
// 13.171 us; speedup vs baseline: 3.6524x; 3.6524x over previous
//
#include <hip/hip_runtime.h>

// Masked LSTM encoder — two-kernel split (R3 structure, best measured: 13.11 us).
//  - h0 = c0 = 0 -> step 0 is gates = x0 @ Wx + b; the f-gate is dead (c0=0),
//    so only i,g,o columns (1536 of 2048) are ever computed.
//  - is_eos[b] |= (embedding[token][EOS_ID=1] != 0): a N(0,0.02) float -> true
//    after step 0 with probability 1, freezing (c,h) at step-0 values.
//  - K1: split-K GEMM partials for x0@Wx; 64-col tiles keep every 64B Wx line
//    EXCLUSIVE to one block (R5 proved narrow tiles -> 8x fetch amplification);
//    lane=batch -> wave-uniform Wx addresses -> scalar s_loads; LDS transpose
//    so global stores are coalesced in [ec][b][col].
//  - K2: one block per batch owns the whole state vector -> reduce + bias +
//    pointwise + eos flag + faithful sequential tail fused (tail exits
//    immediately on this input; no cross-block dependencies).
//  - Fusion attempts into ONE launch all regressed: R4 (1 block/CU serialization,
//    15.6), R5 (narrow tiles, 21.3), R7 (cooperative launch, 48.1). Two plain
//    launches is the structural optimum on this harness.

#define SEQ      512
#define EDIM     512
#define HDIM     512
#define BATCH    64
#define NCOMPACT 1536          // compact cols: i(0..511), g(512..1023), o(1024..1535)
#define ECHUNKS  8             // split-K factor
#define ELEN     (EDIM / ECHUNKS)   // 64
#define CTILES   (NCOMPACT / 64)    // 24

__device__ __forceinline__ float sigf(float x) { return 1.0f / (1.0f + __expf(-x)); }

// ---- K1: partial GEMM, 192 blocks x 512. Block = 64 compact cols x 64-e chunk.
// lane (t&63) = batch; wave (t>>6) = 8 consecutive cols (wave-uniform -> s_load).
__global__ __launch_bounds__(512) void gemm_partial_kernel(
    const int* __restrict__ inputs, const float* __restrict__ emb,
    const float* __restrict__ Wx, float* __restrict__ partials)
{
    const int ct   = blockIdx.x >> 3;      // 0..23  compact col tile
    const int ec   = blockIdx.x & 7;       // 0..7   e-chunk
    const int e0   = ec * ELEN;
    const int t    = threadIdx.x;
    const int lane = t & 63;               // = batch in compute phase
    const int w    = __builtin_amdgcn_readfirstlane(t >> 6);  // wave 0..7
    const int gate = ct >> 3;              // 0:i 1:g 2:o
    const int gofs = (gate == 0) ? 0 : (gate == 1 ? 1024 : 1536);
    const int wcol = gofs + (ct & 7) * 64 + w * 8;  // original Wx col, wave-uniform

    __shared__ float x_s[ELEN][BATCH + 1];  // [e][b]: writes & reads conflict-free
    __shared__ float g_s[64][BATCH + 1];    // [cc_local][b]: transpose buffer

    // Stage x chunk: wave w stages batches w*8..w*8+7; lane sweeps e (coalesced
    // global read; LDS write addr = lane*65+b -> consecutive banks, free).
    #pragma unroll
    for (int k = 0; k < 8; ++k) {
        const int b   = w * 8 + k;
        const int tok = inputs[b * SEQ];
        x_s[lane][b] = emb[(size_t)tok * EDIM + e0 + lane];
    }
    __syncthreads();

    float acc[8] = {};
    #pragma unroll 8
    for (int e = 0; e < ELEN; ++e) {
        const float xv = x_s[e][lane];                    // conflict-free b32
        const float* row = Wx + (size_t)(e0 + e) * 2048 + wcol;  // wave-uniform
        #pragma unroll
        for (int wc = 0; wc < 8; ++wc)
            acc[wc] += xv * row[wc];                      // scalar-loadable Wx
    }

    // Transpose through LDS so global stores are coalesced in [ec][b][cc].
    #pragma unroll
    for (int wc = 0; wc < 8; ++wc)
        g_s[w * 8 + wc][lane] = acc[wc];                  // lanes consecutive: free
    __syncthreads();

    #pragma unroll
    for (int k = 0; k < 8; ++k) {
        const int b = w * 8 + k;
        // read g_s[lane][b]: bank (lane+b)%32 -> 2-way, free. store coalesced.
        partials[((size_t)ec * BATCH + b) * NCOMPACT + ct * 64 + lane] = g_s[lane][b];
    }
}

// ---- K2: one block per batch. Reduce partials + bias + pointwise LSTM,
// recompute eos flag locally, run faithful tail only if not frozen.
__global__ __launch_bounds__(512) void reduce_pointwise_tail_kernel(
    const int* __restrict__ inputs, const float* __restrict__ emb,
    const float* __restrict__ Wx, const float* __restrict__ Wh,
    const float* __restrict__ bias, const float* __restrict__ partials,
    float* __restrict__ out)
{
    const int b = blockIdx.x;
    const int j = threadIdx.x;              // 0..511

    __shared__ float h_s[HDIM];
    __shared__ float c_s[HDIM];
    __shared__ float x_s[EDIM];

    float gi = bias[j];
    float gg = bias[1024 + j];
    float go = bias[1536 + j];
    #pragma unroll
    for (int ec = 0; ec < ECHUNKS; ++ec) {
        const float* p = partials + ((size_t)ec * BATCH + b) * NCOMPACT;
        gi += p[j];                          // coalesced (lanes = j)
        gg += p[512 + j];
        go += p[1024 + j];
    }

    float c = sigf(gi) * tanhf(gg);          // c0 = 0 -> f-gate dead
    float h = sigf(go) * tanhf(c);

    // EOS after step 0 (block-uniform; broadcast loads).
    const int tok0 = inputs[b * SEQ];
    const bool frozen = (emb[(size_t)tok0 * EDIM + 1] != 0.0f);

    if (frozen) {                            // block-uniform branch
        out[b * HDIM + j]                = c;
        out[BATCH * HDIM + b * HDIM + j] = h;
        return;
    }

    // Faithful sequential tail, steps 1..511 (never taken on this input).
    c_s[j] = c;
    h_s[j] = h;
    bool eos = false;
    __syncthreads();

    const float b0 = bias[j];
    const float b1 = bias[512 + j];
    const float b2 = bias[1024 + j];
    const float b3 = bias[1536 + j];

    for (int s = 1; s < SEQ; ++s) {
        const int tok = inputs[b * SEQ + s];
        x_s[j] = emb[(size_t)tok * EDIM + j];
        __syncthreads();

        float g0 = b0, g1 = b1, g2 = b2, g3 = b3;
        for (int e = 0; e < EDIM; ++e) {
            const float xv = x_s[e];
            const float hv = h_s[e];
            const float* wxr = Wx + (size_t)e * 2048;
            const float* whr = Wh + (size_t)e * 2048;
            g0 += xv * wxr[j]        + hv * whr[j];
            g1 += xv * wxr[512 + j]  + hv * whr[512 + j];
            g2 += xv * wxr[1024 + j] + hv * whr[1024 + j];
            g3 += xv * wxr[1536 + j] + hv * whr[1536 + j];
        }
        const float nc = sigf(g1) * c_s[j] + sigf(g0) * tanhf(g2);
        const float nh = sigf(g3) * tanhf(nc);
        eos = eos || (x_s[1] != 0.0f);       // token s raises flag AFTER update
        __syncthreads();
        c_s[j] = nc;
        h_s[j] = nh;
        __syncthreads();
        if (eos) break;                      // block-uniform
    }

    out[b * HDIM + j]                = c_s[j];
    out[BATCH * HDIM + b * HDIM + j] = h_s[j];
}

extern "C" void kernel_launch(void* const* d_in, const int* in_sizes, int n_in,
                              void* d_out, int out_size, void* d_ws, size_t ws_size,
                              hipStream_t stream) {
    const int*   inputs = (const int*)  d_in[0];
    const float* emb    = (const float*)d_in[1];
    const float* Wx     = (const float*)d_in[2];
    const float* Wh     = (const float*)d_in[3];
    const float* bias   = (const float*)d_in[4];
    float* out      = (float*)d_out;
    float* partials = (float*)d_ws;   // ECHUNKS*BATCH*NCOMPACT floats = 3 MB

    gemm_partial_kernel<<<CTILES * ECHUNKS, 512, 0, stream>>>(inputs, emb, Wx, partials);
    reduce_pointwise_tail_kernel<<<BATCH, 512, 0, stream>>>(
        inputs, emb, Wx, Wh, bias, partials, out);
}